// Round 4
// baseline (250.811 us; speedup 1.0000x reference)
//
#include <hip/hip_runtime.h>

#define NN 1024
#define FF 64
#define CC 4
#define EE 32768
#define HH 256

// ---- workspace layout (units of 4-byte words) ----
#define OFF_CNT1   0u         // 4096 i   (c,dst) bucket counts
#define OFF_OFFS1  4096u      // 4097 i
#define OFF_CUR1   8196u      // 4096 i
#define OFF_CNT2   12292u     // 1024 i   tile bucket counts (16B aligned)
#define OFF_OFFS2  13316u     // 1025 i
#define OFF_CUR2   14344u     // 1024 i
#define OFF_SRTS   15368u     // 131072 i sorted src by (c,dst)
#define OFF_SRTW   146440u    // 131072 f sorted w   by (c,dst)
#define OFF_TL     277512u    // 262144 i (int2 per edge) tile-sorted list
#define OFF_P      539656u    // 262144 f
#define OFF_Q      801800u    // 262144 f
// end 1063944 words = 4.26 MB

// ---------------------------------------------------------------------------
// counts for both sorts: (c,dst) buckets and 32x32 tile buckets
__global__ __launch_bounds__(256)
void k_count(const int* __restrict__ ei, int* __restrict__ cnt1, int* __restrict__ cnt2)
{
    unsigned t = blockIdx.x * 256u + threadIdx.x;   // t < C*E
    unsigned e = t & (EE - 1u);
    unsigned c = t >> 15;
    int src = ei[c * 2 * EE + e];
    int dst = ei[c * 2 * EE + EE + e];
    atomicAdd(&cnt1[c * NN + dst], 1);
    atomicAdd(&cnt2[(src >> 5) * 32 + (dst >> 5)], 1);
}

// ---------------------------------------------------------------------------
// exclusive prefix sums: 4096 (16/thread) and 1024 (4/thread), shfl-based
__global__ __launch_bounds__(256)
void k_scan(const int* __restrict__ cnt1, int* __restrict__ offs1, int* __restrict__ cur1,
            const int* __restrict__ cnt2, int* __restrict__ offs2, int* __restrict__ cur2)
{
    __shared__ int ws1[4], ws2[4];
    const int t = threadIdx.x;
    const int w = t >> 6;
    // ---- scan over 4096
    {
        int c[16]; int s = 0;
        const int4* cp = (const int4*)(cnt1 + t * 16);
#pragma unroll
        for (int u = 0; u < 4; ++u) {
            int4 v = cp[u];
            c[u * 4 + 0] = v.x; c[u * 4 + 1] = v.y; c[u * 4 + 2] = v.z; c[u * 4 + 3] = v.w;
            s += v.x + v.y + v.z + v.w;
        }
        int incl = s;
#pragma unroll
        for (int d = 1; d < 64; d <<= 1) {
            int v = __shfl_up(incl, d, 64);
            if ((t & 63) >= d) incl += v;
        }
        if ((t & 63) == 63) ws1[w] = incl;
        __syncthreads();
        int base = incl - s;
        for (int ww = 0; ww < w; ++ww) base += ws1[ww];
        int run = base;
#pragma unroll
        for (int u = 0; u < 16; ++u) {
            offs1[t * 16 + u] = run;
            cur1[t * 16 + u] = run;
            run += c[u];
        }
        if (t == 255) offs1[4096] = run;
    }
    __syncthreads();
    // ---- scan over 1024
    {
        int4 v = ((const int4*)cnt2)[t];
        int s = v.x + v.y + v.z + v.w;
        int incl = s;
#pragma unroll
        for (int d = 1; d < 64; d <<= 1) {
            int vv = __shfl_up(incl, d, 64);
            if ((t & 63) >= d) incl += vv;
        }
        if ((t & 63) == 63) ws2[w] = incl;
        __syncthreads();
        int base = incl - s;
        for (int ww = 0; ww < w; ++ww) base += ws2[ww];
        offs2[t * 4]     = base;             cur2[t * 4]     = base;
        offs2[t * 4 + 1] = base + v.x;       cur2[t * 4 + 1] = base + v.x;
        offs2[t * 4 + 2] = base + v.x + v.y; cur2[t * 4 + 2] = base + v.x + v.y;
        offs2[t * 4 + 3] = base + v.x + v.y + v.z;
        cur2[t * 4 + 3]  = base + v.x + v.y + v.z;
        if (t == 255) offs2[1024] = base + s;
    }
}

// ---------------------------------------------------------------------------
// scatter into both sorted layouts
__global__ __launch_bounds__(256)
void k_bucket(const int* __restrict__ ei, const float* __restrict__ ew,
              int* __restrict__ cur1, int* __restrict__ srt_src, float* __restrict__ srt_w,
              int* __restrict__ cur2, int2* __restrict__ tl)
{
    unsigned t = blockIdx.x * 256u + threadIdx.x;
    unsigned e = t & (EE - 1u);
    unsigned c = t >> 15;
    int src = ei[c * 2 * EE + e];
    int dst = ei[c * 2 * EE + EE + e];
    float w = ew[c * EE + e];
    int pos1 = atomicAdd(&cur1[c * NN + dst], 1);
    srt_src[pos1] = src;
    srt_w[pos1] = w;
    int pos2 = atomicAdd(&cur2[(src >> 5) * 32 + (dst >> 5)], 1);
    tl[pos2] = make_int2((src << 12) | (dst << 2) | (int)c, __float_as_int(w));
}

// ---------------------------------------------------------------------------
// Fused node pipeline: gather -> mlp1 -> mlp2 -> P/Q.  2 nodes / 512-thread
// block, 512 blocks (2 blocks/CU). agg/hid/xn live only in LDS.
__global__ __launch_bounds__(512)
void k_node(const float* __restrict__ x, const int* __restrict__ offs,
            const int* __restrict__ srt_src, const float* __restrict__ srt_w,
            const float* __restrict__ Wn1, const float* __restrict__ bn1,
            const float* __restrict__ Wn2, const float* __restrict__ bn2,
            const float* __restrict__ We1, const float* __restrict__ be1,
            const float* __restrict__ epsp,
            float* __restrict__ P, float* __restrict__ Q)
{
    __shared__ float hval[2][256];
    __shared__ float hidl[2][256];
    __shared__ float part[4][2][64];
    __shared__ float xnl[2][64];
    const int tid = threadIdx.x;
    const int n0 = blockIdx.x * 2;

    // gather: wave w -> bucket (c = w&3, node = n0 + (w>>2)), lane = f
    {
        const int w = tid >> 6, lane = tid & 63;
        const int c = w & 3, nn = w >> 2;
        const int g = c * NN + (n0 + nn);
        const int beg = offs[g], end = offs[g + 1];
        float acc = 0.f;
        for (int k = beg; k < end; ++k)
            acc += x[srt_src[k] * FF + lane] * srt_w[k];
        const float ope = 1.0f + epsp[0];
        hval[nn][c * 64 + lane] = acc + ope * x[(n0 + nn) * FF + lane];
    }
    __syncthreads();

    // mlp1
    {
        const int nn = tid >> 8, h = tid & 255;
        float acc = bn1[h];
#pragma unroll 8
        for (int k = 0; k < 256; ++k)
            acc += hval[nn][k] * Wn1[k * 256 + h];
        hidl[nn][h] = fmaxf(acc, 0.f);
    }
    __syncthreads();

    // mlp2 partials over 4 k-quarters
    {
        const int kq = tid >> 7, nn = (tid >> 6) & 1, f = tid & 63;
        float p = 0.f;
#pragma unroll 8
        for (int k = kq * 64; k < kq * 64 + 64; ++k)
            p += hidl[nn][k] * Wn2[k * 64 + f];
        part[kq][nn][f] = p;
    }
    __syncthreads();
    if (tid < 128) {
        const int nn = tid >> 6, f = tid & 63;
        xnl[nn][f] = bn2[f] + part[0][nn][f] + part[1][nn][f]
                             + part[2][nn][f] + part[3][nn][f];
    }
    __syncthreads();

    // P/Q projection
    {
        const int r = tid >> 8, h = tid & 255;
        float p = be1[h], q = 0.f;
#pragma unroll 8
        for (int f = 0; f < 64; ++f) {
            float xv = xnl[r][f];
            p += xv * We1[(4 + f) * 256 + h];
            q += xv * We1[(68 + f) * 256 + h];
        }
        P[(n0 + r) * 256 + h] = p;
        Q[(n0 + r) * 256 + h] = q;
    }
}

// ---------------------------------------------------------------------------
// Edge MLP: uniform pass relu(P+Q)@We2 (6 VALU/hidden, no a-term) plus
// compacted sparse fixup  sum_h [relu(pre+s)-relu(pre)]*We2  per edge-pair.
// 32x32 tile / block, 256 threads, 2x2 pairs/thread, H chunked 4x64.
__global__ __launch_bounds__(256, 3)
void k_edge_mlp(const float* __restrict__ P, const float* __restrict__ Q,
                const int* __restrict__ toffs, const int2* __restrict__ tl,
                const float* __restrict__ We1, const float* __restrict__ We2,
                const float* __restrict__ be2, float* __restrict__ out)
{
    __shared__ float4 aT[32 * 32];    // 16 KB dense a-tile [li*32+lj]
    __shared__ float4 corr[32 * 32];  // 16 KB per-pair correction
    __shared__ float4 Pl[32 * 16];    // 8 KB [row][q ^ ((row>>1)&7)]
    __shared__ float4 Ql[32 * 16];    // 8 KB
    __shared__ unsigned short list[1024];
    __shared__ int nList;

    const int tid = threadIdx.x;
    const int bi = blockIdx.y, bj = blockIdx.x;
    const int iBase = bi * 32, jBase = bj * 32;
    const int tile = bi * 32 + bj;

    // phase 0: zero aT, corr, nList
#pragma unroll
    for (int u = 0; u < 4; ++u) {
        aT[tid + u * 256]   = make_float4(0.f, 0.f, 0.f, 0.f);
        corr[tid + u * 256] = make_float4(0.f, 0.f, 0.f, 0.f);
    }
    if (tid == 0) nList = 0;
    __syncthreads();

    // phase 1: build a-tile from tile-sorted edge list (handles duplicates)
    {
        const int beg = toffs[tile], n = toffs[tile + 1] - beg;
        float* aTf = (float*)aT;
        for (int k = tid; k < n; k += 256) {
            int2 ent = tl[beg + k];
            int li = (ent.x >> 12) & 31, lj = (ent.x >> 2) & 31, c = ent.x & 3;
            atomicAdd(&aTf[(li * 32 + lj) * 4 + c], __int_as_float(ent.y));
        }
    }
    __syncthreads();

    // phase 2: compact nonzero pairs
#pragma unroll
    for (int u = 0; u < 4; ++u) {
        int p = tid * 4 + u;
        float4 a4 = aT[p];
        if (a4.x != 0.f || a4.y != 0.f || a4.z != 0.f || a4.w != 0.f) {
            int idx = atomicAdd(&nList, 1);
            list[idx] = (unsigned short)p;
        }
    }
    __syncthreads();
    const int nL = nList;

    const int tx = tid & 15, ty = tid >> 4;
    const int psw = ty & 7, qsw = tx & 7;

    float4 acc[2][2];
#pragma unroll
    for (int ii = 0; ii < 2; ++ii)
#pragma unroll
        for (int jj = 0; jj < 2; ++jj)
            acc[ii][jj] = make_float4(0.f, 0.f, 0.f, 0.f);

    for (int hc = 0; hc < 4; ++hc) {
        // stage P/Q chunk (prev readers done via loop-end barrier)
#pragma unroll
        for (int u = 0; u < 2; ++u) {
            int idx = tid + u * 256;
            int row = idx >> 4, q = idx & 15;
            int ph = q ^ ((row >> 1) & 7);
            Pl[row * 16 + ph] = *(const float4*)(P + (iBase + row) * 256 + hc * 64 + q * 4);
            Ql[row * 16 + ph] = *(const float4*)(Q + (jBase + row) * 256 + hc * 64 + q * 4);
        }
        __syncthreads();

        // uniform pass: 6 VALU per hidden value, no a-term
#pragma unroll 4
        for (int q = 0; q < 16; ++q) {
            float4 w2[4];
#pragma unroll
            for (int k = 0; k < 4; ++k)
                w2[k] = *(const float4*)(We2 + (hc * 64 + q * 4 + k) * 4);
            float4 p[2], qv[2];
#pragma unroll
            for (int r = 0; r < 2; ++r) p[r]  = Pl[(ty * 2 + r) * 16 + (q ^ psw)];
#pragma unroll
            for (int r = 0; r < 2; ++r) qv[r] = Ql[(tx * 2 + r) * 16 + (q ^ qsw)];
#pragma unroll
            for (int ii = 0; ii < 2; ++ii) {
#pragma unroll
                for (int jj = 0; jj < 2; ++jj) {
                    float v0 = fmaxf(p[ii].x + qv[jj].x, 0.f);
                    float v1 = fmaxf(p[ii].y + qv[jj].y, 0.f);
                    float v2 = fmaxf(p[ii].z + qv[jj].z, 0.f);
                    float v3 = fmaxf(p[ii].w + qv[jj].w, 0.f);
                    acc[ii][jj].x += v0 * w2[0].x + v1 * w2[1].x + v2 * w2[2].x + v3 * w2[3].x;
                    acc[ii][jj].y += v0 * w2[0].y + v1 * w2[1].y + v2 * w2[2].y + v3 * w2[3].y;
                    acc[ii][jj].z += v0 * w2[0].z + v1 * w2[1].z + v2 * w2[2].z + v3 * w2[3].z;
                    acc[ii][jj].w += v0 * w2[0].w + v1 * w2[1].w + v2 * w2[2].w + v3 * w2[3].w;
                }
            }
        }

        // sparse fixup: one thread per compacted pair
        for (int en = tid; en < nL; en += 256) {
            int p = list[en];
            int li = p >> 5, lj = p & 31;
            float4 a4 = aT[p];
            float4 cc = corr[p];
            const int ps2 = (li >> 1) & 7, qs2 = (lj >> 1) & 7;
#pragma unroll 4
            for (int q = 0; q < 16; ++q) {
                float4 w1[4], w2[4];
#pragma unroll
                for (int c = 0; c < 4; ++c)
                    w1[c] = *(const float4*)(We1 + c * 256 + hc * 64 + q * 4);
#pragma unroll
                for (int k = 0; k < 4; ++k)
                    w2[k] = *(const float4*)(We2 + (hc * 64 + q * 4 + k) * 4);
                float4 pv = Pl[li * 16 + (q ^ ps2)];
                float4 qv = Ql[lj * 16 + (q ^ qs2)];
                float s0 = a4.x * w1[0].x + a4.y * w1[1].x + a4.z * w1[2].x + a4.w * w1[3].x;
                float s1 = a4.x * w1[0].y + a4.y * w1[1].y + a4.z * w1[2].y + a4.w * w1[3].y;
                float s2 = a4.x * w1[0].z + a4.y * w1[1].z + a4.z * w1[2].z + a4.w * w1[3].z;
                float s3 = a4.x * w1[0].w + a4.y * w1[1].w + a4.z * w1[2].w + a4.w * w1[3].w;
                float b0 = pv.x + qv.x, b1 = pv.y + qv.y, b2_ = pv.z + qv.z, b3 = pv.w + qv.w;
                float d0 = fmaxf(b0 + s0, 0.f) - fmaxf(b0, 0.f);
                float d1 = fmaxf(b1 + s1, 0.f) - fmaxf(b1, 0.f);
                float d2 = fmaxf(b2_ + s2, 0.f) - fmaxf(b2_, 0.f);
                float d3 = fmaxf(b3 + s3, 0.f) - fmaxf(b3, 0.f);
                cc.x += d0 * w2[0].x + d1 * w2[1].x + d2 * w2[2].x + d3 * w2[3].x;
                cc.y += d0 * w2[0].y + d1 * w2[1].y + d2 * w2[2].y + d3 * w2[3].y;
                cc.z += d0 * w2[0].z + d1 * w2[1].z + d2 * w2[2].z + d3 * w2[3].z;
                cc.w += d0 * w2[0].w + d1 * w2[1].w + d2 * w2[2].w + d3 * w2[3].w;
            }
            corr[p] = cc;   // single writer per pair
        }
        __syncthreads();
    }

    const float4 b2 = *(const float4*)be2;
#pragma unroll
    for (int ii = 0; ii < 2; ++ii)
#pragma unroll
        for (int jj = 0; jj < 2; ++jj) {
            int p = (ty * 2 + ii) * 32 + (tx * 2 + jj);
            float4 cr = corr[p];
            float4 o = acc[ii][jj];
            o.x += b2.x + cr.x; o.y += b2.y + cr.y;
            o.z += b2.z + cr.z; o.w += b2.w + cr.w;
            *(float4*)(out + ((size_t)(iBase + ty * 2 + ii) * NN + (jBase + tx * 2 + jj)) * 4) = o;
        }
}

// ---------------------------------------------------------------------------
extern "C" void kernel_launch(void* const* d_in, const int* in_sizes, int n_in,
                              void* d_out, int out_size, void* d_ws, size_t ws_size,
                              hipStream_t stream)
{
    (void)in_sizes; (void)n_in; (void)out_size; (void)ws_size;
    const float* x   = (const float*)d_in[0];
    const int*   ei  = (const int*)d_in[1];
    const float* ew  = (const float*)d_in[2];
    const float* Wn1 = (const float*)d_in[3];
    const float* bn1 = (const float*)d_in[4];
    const float* Wn2 = (const float*)d_in[5];
    const float* bn2 = (const float*)d_in[6];
    const float* We1 = (const float*)d_in[7];
    const float* be1 = (const float*)d_in[8];
    const float* We2 = (const float*)d_in[9];
    const float* be2 = (const float*)d_in[10];
    const float* eps = (const float*)d_in[11];
    float* out = (float*)d_out;

    float* ws = (float*)d_ws;
    int*   cnt1  = (int*)(ws + OFF_CNT1);
    int*   offs1 = (int*)(ws + OFF_OFFS1);
    int*   cur1  = (int*)(ws + OFF_CUR1);
    int*   cnt2  = (int*)(ws + OFF_CNT2);
    int*   offs2 = (int*)(ws + OFF_OFFS2);
    int*   cur2  = (int*)(ws + OFF_CUR2);
    int*   srts  = (int*)(ws + OFF_SRTS);
    float* srtw  = ws + OFF_SRTW;
    int2*  tl    = (int2*)(ws + OFF_TL);
    float* Pb    = ws + OFF_P;
    float* Qb    = ws + OFF_Q;

    // zero both counter arrays (covers cnt1..cnt2 range, 53 KB)
    hipMemsetAsync(d_ws, 0, (size_t)13316 * sizeof(int), stream);

    k_count <<<(CC * EE) / 256, 256, 0, stream>>>(ei, cnt1, cnt2);
    k_scan  <<<1, 256, 0, stream>>>(cnt1, offs1, cur1, cnt2, offs2, cur2);
    k_bucket<<<(CC * EE) / 256, 256, 0, stream>>>(ei, ew, cur1, srts, srtw, cur2, tl);
    k_node  <<<NN / 2, 512, 0, stream>>>(x, offs1, srts, srtw,
                                         Wn1, bn1, Wn2, bn2, We1, be1, eps, Pb, Qb);

    dim3 g(NN / 32, NN / 32);
    k_edge_mlp<<<g, 256, 0, stream>>>(Pb, Qb, offs2, tl, We1, We2, be2, out);
}